// Round 12
// baseline (1606.513 us; speedup 1.0000x reference)
//
#include <hip/hip_runtime.h>
#include <hip/hip_bf16.h>

#define B_ 256
#define T_ 400
#define NMELS 80
#define INP 512
#define DEC_ 128
#define LSTM_ 1024
#define FILT 32
#define KS 31
#define MAXR 20
#define TCH 4

typedef float f32x4 __attribute__((ext_vector_type(4)));
typedef short bf16x8 __attribute__((ext_vector_type(8)));

__device__ __forceinline__ short f2bf(float f) {
  union { float f; unsigned u; } v; v.f = f;
  unsigned u = v.u;
  unsigned r = (u + 0x7fffu + ((u >> 16) & 1u)) >> 16;
  return (short)r;
}

__device__ __forceinline__ bf16x8 pack8(float4 a0, float4 a1) {
  bf16x8 r;
  r[0] = f2bf(a0.x); r[1] = f2bf(a0.y); r[2] = f2bf(a0.z); r[3] = f2bf(a0.w);
  r[4] = f2bf(a1.x); r[5] = f2bf(a1.y); r[6] = f2bf(a1.z); r[7] = f2bf(a1.w);
  return r;
}

__device__ __forceinline__ float sigmoidf_(float x) {
  return 1.f / (1.f + __expf(-x));
}
__device__ __forceinline__ float tanhf_(float x) {
  float e = __expf(2.f * x);
  return 1.f - 2.f / (e + 1.f);
}

// ---------------------------------------------------------------------------
struct Args {
  const float *enc, *esp, *prein, *ah0, *h1_0, *h2_0, *c1_0, *c2_0, *ctx0, *cum;
  const int* chars;
  const float *pw1, *pb1, *pw2, *pb2;
  const float *gwih, *gwhh, *gbih, *gbhh;
  const float *cvw, *cvb, *lsaL, *lsaW, *lsaWb, *lsav;
  const float *riw, *rib;
  const float *l1wih, *l1whh, *l1bih, *l1bhh;
  const float *l2wih, *l2whh, *l2bih, *l2bhh;
  const float *melw, *stopw, *stopb;
  float *o_mels, *o_scores, *o_attn, *o_h1, *o_h2, *o_c1, *o_c2, *o_ctx, *o_stop, *o_cum;
  float *ws_h, *ws_pre2, *ws_gi2, *ws_pq, *ws_u, *ws_part, *ws_x, *ws_x2, *ws_x3, *ws_g4;
  unsigned* bar;
};

// LDS overlays
struct SmemGemm { short sA[64][40]; short sB[64][40]; };
struct SmemAttn {
  float s_cum[232]; float s_w[FILT * KS]; float s_cb[FILT];
  float s_pq[DEC_]; float s_v[DEC_];
  short s_conv[208][40]; short s_L[128][40];
};
struct SmemCtx { float s_u[T_]; float s_red[8]; };
struct SmemGru { float s_h[DEC_]; float s_gh[3 * DEC_]; float s_h2[DEC_]; };
struct SmemMel { float s_x[LSTM_]; float s_c[INP]; float s_red[4]; };

#define SMEM_BYTES 33024

// ---------------------------------------------------------------------------
// Grid barrier v3: RELAXED polling, single release fence before arrival,
// single acquire fence after release. Bounded spin -> fail fast, never hang.
// ---------------------------------------------------------------------------
__device__ __forceinline__ void grid_bar(unsigned* cnt, unsigned& epoch) {
  __syncthreads();
  if (threadIdx.x == 0) {
    epoch += gridDim.x;
    __threadfence();   // release: drain this block's writes (wbL2 once)
    __hip_atomic_fetch_add(cnt, 1u, __ATOMIC_RELAXED, __HIP_MEMORY_SCOPE_AGENT);
    unsigned spin = 0;
    while (__hip_atomic_load(cnt, __ATOMIC_RELAXED, __HIP_MEMORY_SCOPE_AGENT) < epoch) {
      __builtin_amdgcn_s_sleep(64);
      if (++spin > (1u << 21)) break;   // ~seconds; fail via absmax, not timeout
    }
    __threadfence();   // acquire: invalidate stale lines once
  }
  __syncthreads();
}

// ---------------------------------------------------------------------------
// Tiled bf16-MFMA GEMM phase, grid-stride over (tx * ty * tz) tiles.
// zmode: 0 = full (bias); 1 = z is pair idx (partials, no bias);
//        2 = z = pair*2 + K-half (partials, no bias).
// ---------------------------------------------------------------------------
__device__ void gemm_phase(
    const float* __restrict__ A1, int lda1, const float* __restrict__ W1, int ldw1, int K1,
    const float* __restrict__ A2, int lda2, const float* __restrict__ W2, int ldw2, int K2,
    const float* __restrict__ bias1, const float* __restrict__ bias2,
    float* __restrict__ out, int ldo, int act, int zmode,
    int tx, int ty, int tz, int Mrows, char* smraw)
{
  SmemGemm* sm = (SmemGemm*)smraw;
  const int tid  = threadIdx.x;
  const int lane = tid & 63;
  const int wave = tid >> 6;
  const int wr = (wave >> 1) * 32;
  const int wc = (wave & 1) * 32;
  const int sr = tid >> 2;
  const int sk = (tid & 3) * 8;
  const int l15 = lane & 15;
  const int kq  = (lane >> 4) * 8;
  const int ntile = tx * ty * tz;

  for (int tile = blockIdx.x; tile < ntile; tile += gridDim.x) {
    const int bz = tile / (tx * ty);
    const int r2 = tile - bz * tx * ty;
    const int by = r2 / tx, bx = r2 - by * tx;
    const int bm = by * 64, bn = bx * 64;

    int kb1 = 0, ke1 = K1, kb2 = 0, ke2 = K2;
    if (zmode == 1) {
      if (bz == 0) ke2 = 0; else ke1 = 0;
    } else if (zmode == 2) {
      int p = bz >> 1, h = bz & 1;
      if (p == 0) { ke2 = 0; int half = K1 >> 1; kb1 = h * half; ke1 = kb1 + half; }
      else        { ke1 = 0; int half = K2 >> 1; kb2 = h * half; ke2 = kb2 + half; }
    }
    float* outp = out + (zmode > 0 ? (size_t)bz * Mrows * ldo : (size_t)0);

    f32x4 acc[2][2];
#pragma unroll
    for (int i = 0; i < 2; ++i)
#pragma unroll
      for (int j = 0; j < 2; ++j) acc[i][j] = (f32x4){0.f, 0.f, 0.f, 0.f};

    for (int pair = 0; pair < 2; ++pair) {
      const int kb = pair ? kb2 : kb1;
      const int ke = pair ? ke2 : ke1;
      if (ke <= kb) continue;
      const float* A = pair ? A2 : A1;
      const float* W = pair ? W2 : W1;
      const int lda = pair ? lda2 : lda1;
      const int ldw = pair ? ldw2 : ldw1;
      const float* arow = A + (size_t)(bm + sr) * lda;
      const float* wrow = W + (size_t)(bn + sr) * ldw;

      float4 ra0, ra1, rb0, rb1;
      if (kb + 32 <= ke) {
        const float* pa = arow + kb + sk;
        const float* pw = wrow + kb + sk;
        ra0 = *(const float4*)pa; ra1 = *(const float4*)(pa + 4);
        rb0 = *(const float4*)pw; rb1 = *(const float4*)(pw + 4);
      }
      for (int k0 = kb; k0 < ke; k0 += 32) {
        __syncthreads();
        if (k0 + 32 <= ke) {
          *(bf16x8*)&sm->sA[sr][sk] = pack8(ra0, ra1);
          *(bf16x8*)&sm->sB[sr][sk] = pack8(rb0, rb1);
          if (k0 + 64 <= ke) {
            const float* pa = arow + k0 + 32 + sk;
            const float* pw = wrow + k0 + 32 + sk;
            ra0 = *(const float4*)pa; ra1 = *(const float4*)(pa + 4);
            rb0 = *(const float4*)pw; rb1 = *(const float4*)(pw + 4);
          }
        } else {  // K tail (prenet1)
          short* da = &sm->sA[sr][sk];
          short* db = &sm->sB[sr][sk];
#pragma unroll
          for (int j = 0; j < 8; ++j) {
            int k = k0 + sk + j;
            da[j] = (k < ke) ? f2bf(arow[k]) : (short)0;
            db[j] = (k < ke) ? f2bf(wrow[k]) : (short)0;
          }
        }
        __syncthreads();
        bf16x8 af[2], bfv[2];
        af[0]  = *(const bf16x8*)&sm->sA[wr + l15][kq];
        af[1]  = *(const bf16x8*)&sm->sA[wr + 16 + l15][kq];
        bfv[0] = *(const bf16x8*)&sm->sB[wc + l15][kq];
        bfv[1] = *(const bf16x8*)&sm->sB[wc + 16 + l15][kq];
#pragma unroll
        for (int i = 0; i < 2; ++i)
#pragma unroll
          for (int j = 0; j < 2; ++j)
            acc[i][j] = __builtin_amdgcn_mfma_f32_16x16x32_bf16(af[i], bfv[j], acc[i][j], 0, 0, 0);
      }
    }

#pragma unroll
    for (int i = 0; i < 2; ++i) {
#pragma unroll
      for (int j = 0; j < 2; ++j) {
        int n = bn + wc + j * 16 + l15;
        float bv = 0.f;
        if (zmode == 0) bv = (bias1 ? bias1[n] : 0.f) + (bias2 ? bias2[n] : 0.f);
#pragma unroll
        for (int r = 0; r < 4; ++r) {
          int m = bm + wr + i * 16 + (lane >> 4) * 4 + r;
          float v = acc[i][j][r] + bv;
          if (act == 1) v = fmaxf(v, 0.f);
          outp[(size_t)m * ldo + n] = v;
        }
      }
    }
    __syncthreads();
  }
}

// ---------------------------------------------------------------------------
#define GI_SEG (B_ * 384)
__device__ void gru_phase(const Args& a, char* smraw) {
  SmemGru* sm = (SmemGru*)smraw;
  const int tid = threadIdx.x;
  for (int b = blockIdx.x; b < B_; b += gridDim.x) {
    __syncthreads();
    if (tid < DEC_) sm->s_h[tid] = a.ah0[(size_t)b * DEC_ + tid];
    __syncthreads();
    for (int n = tid; n < 3 * DEC_; n += 256) {
      const float4* wr4 = (const float4*)(a.gwhh + (size_t)n * DEC_);
      float ax = 0.f, ay = 0.f, az = 0.f, aw = 0.f;
#pragma unroll
      for (int q = 0; q < DEC_ / 4; ++q) {
        float4 w = wr4[q];
        ax += w.x * sm->s_h[q * 4];
        ay += w.y * sm->s_h[q * 4 + 1];
        az += w.z * sm->s_h[q * 4 + 2];
        aw += w.w * sm->s_h[q * 4 + 3];
      }
      sm->s_gh[n] = a.gbhh[n] + ax + ay + az + aw;
    }
    __syncthreads();
    if (tid < DEC_) {
      size_t base = (size_t)b * 384;
      const float* gp = a.ws_gi2;
      float gir = gp[base + tid]       + gp[GI_SEG + base + tid]       + a.gbih[tid];
      float giz = gp[base + 128 + tid] + gp[GI_SEG + base + 128 + tid] + a.gbih[128 + tid];
      float gin = gp[base + 256 + tid] + gp[GI_SEG + base + 256 + tid] + a.gbih[256 + tid];
      float r = sigmoidf_(gir + sm->s_gh[tid]);
      float z = sigmoidf_(giz + sm->s_gh[128 + tid]);
      float n = tanhf_(gin + r * sm->s_gh[256 + tid]);
      float h = (1.f - z) * n + z * sm->s_h[tid];
      sm->s_h2[tid] = h;
      a.o_attn[(size_t)b * DEC_ + tid] = h;
    }
    __syncthreads();
    if (tid < DEC_) {
      const float4* wr4 = (const float4*)(a.lsaW + (size_t)tid * DEC_);
      float ax = 0.f, ay = 0.f, az = 0.f, aw = 0.f;
#pragma unroll
      for (int q = 0; q < DEC_ / 4; ++q) {
        float4 w = wr4[q];
        ax += w.x * sm->s_h2[q * 4];
        ay += w.y * sm->s_h2[q * 4 + 1];
        az += w.z * sm->s_h2[q * 4 + 2];
        aw += w.w * sm->s_h2[q * 4 + 3];
      }
      a.ws_pq[(size_t)b * DEC_ + tid] = a.lsaWb[tid] + ax + ay + az + aw;
    }
    __syncthreads();
  }
}

// ---------------------------------------------------------------------------
__device__ void attn_phase(const Args& a, char* smraw) {
  SmemAttn* sm = (SmemAttn*)smraw;
  const int tid = threadIdx.x;
  const int lane = tid & 63, wave = tid >> 6;
  const int l15 = lane & 15, kq = (lane >> 4) * 8;

  for (int w = blockIdx.x; w < 2 * B_; w += gridDim.x) {
    const int half = w & 1;
    const int b    = w >> 1;
    const int t0   = half * 200;
    __syncthreads();

    for (int i = tid; i < 230; i += 256) {
      int t = t0 - 15 + i;
      sm->s_cum[i] = (t >= 0 && t < T_) ? a.cum[(size_t)b * T_ + t] : 0.f;
    }
    for (int i = tid; i < FILT * KS; i += 256) sm->s_w[i] = a.cvw[i];
    for (int i = tid; i < DEC_ * FILT; i += 256) sm->s_L[i >> 5][i & 31] = f2bf(a.lsaL[i]);
    if (tid < FILT) sm->s_cb[tid] = a.cvb[tid];
    if (tid < DEC_) { sm->s_pq[tid] = a.ws_pq[(size_t)b * DEC_ + tid]; sm->s_v[tid] = a.lsav[tid]; }
    sm->s_conv[200 + (tid >> 5)][tid & 31] = 0;
    __syncthreads();

    if (tid < 200) {
      float c[KS];
#pragma unroll
      for (int k = 0; k < KS; ++k) c[k] = sm->s_cum[tid + k];
#pragma unroll
      for (int f = 0; f < FILT; ++f) {
        float acc = sm->s_cb[f];
#pragma unroll
        for (int k = 0; k < KS; ++k) acc += c[k] * sm->s_w[f * KS + k];
        sm->s_conv[tid][f] = f2bf(acc);
      }
    }
    __syncthreads();

    for (int m = wave; m < 13; m += 4) {
      bf16x8 af = *(const bf16x8*)&sm->s_conv[m * 16 + l15][kq];
      f32x4 acc[8];
#pragma unroll
      for (int n = 0; n < 8; ++n) {
        bf16x8 bf = *(const bf16x8*)&sm->s_L[n * 16 + l15][kq];
        acc[n] = __builtin_amdgcn_mfma_f32_16x16x32_bf16(af, bf, (f32x4){0.f, 0.f, 0.f, 0.f}, 0, 0, 0);
      }
      const int trow = m * 16 + (lane >> 4) * 4;
      float u[4] = {0.f, 0.f, 0.f, 0.f};
#pragma unroll
      for (int n = 0; n < 8; ++n) {
        int d = n * 16 + l15;
        float pqd = sm->s_pq[d], vd = sm->s_v[d];
#pragma unroll
        for (int r = 0; r < 4; ++r) {
          int tl = trow + r;
          if (tl < 200) {
            float x = acc[n][r] + pqd + a.esp[((size_t)b * T_ + t0 + tl) * DEC_ + d];
            u[r] += tanhf_(x) * vd;
          }
        }
      }
#pragma unroll
      for (int r = 0; r < 4; ++r) {
#pragma unroll
        for (int o = 1; o < 16; o <<= 1) u[r] += __shfl_xor(u[r], o);
      }
      if (l15 == 0) {
#pragma unroll
        for (int r = 0; r < 4; ++r) {
          int tl = trow + r;
          if (tl < 200) {
            int t = t0 + tl;
            float uu = u[r];
            if (a.chars[(size_t)b * T_ + t] == 0) uu = 0.f;
            a.ws_u[(size_t)b * T_ + t] = uu;
          }
        }
      }
    }
    __syncthreads();
  }
}

// ---------------------------------------------------------------------------
// softmax (redundant per tc) + context partial over T-chunk of 100.
// ---------------------------------------------------------------------------
__device__ void ctx_phase(const Args& a, char* smraw) {
  SmemCtx* sm = (SmemCtx*)smraw;
  const int tid = threadIdx.x;
  const int lane = tid & 63, wave = tid >> 6;

  for (int w = blockIdx.x; w < TCH * B_; w += gridDim.x) {
    const int tc = w / B_;
    const int b  = w - tc * B_;
    __syncthreads();

    float mx = -1e30f;
    for (int t = tid; t < T_; t += 256) {
      float v = a.ws_u[(size_t)b * T_ + t];
      sm->s_u[t] = v;
      mx = fmaxf(mx, v);
    }
#pragma unroll
    for (int o = 32; o >= 1; o >>= 1) mx = fmaxf(mx, __shfl_xor(mx, o));
    if (lane == 0) sm->s_red[wave] = mx;
    __syncthreads();
    mx = fmaxf(fmaxf(sm->s_red[0], sm->s_red[1]), fmaxf(sm->s_red[2], sm->s_red[3]));

    float smv = 0.f;
    for (int t = tid; t < T_; t += 256) {
      float e = __expf(sm->s_u[t] - mx);
      sm->s_u[t] = e;
      smv += e;
    }
#pragma unroll
    for (int o = 32; o >= 1; o >>= 1) smv += __shfl_xor(smv, o);
    if (lane == 0) sm->s_red[4 + wave] = smv;
    __syncthreads();
    smv = sm->s_red[4] + sm->s_red[5] + sm->s_red[6] + sm->s_red[7];
    float inv = 1.f / smv;
    for (int t = tid; t < T_; t += 256) {
      float s = sm->s_u[t] * inv;
      sm->s_u[t] = s;
      if (tc == 0) {
        a.o_scores[(size_t)b * T_ + t] = s;
        a.o_cum[(size_t)b * T_ + t] = a.cum[(size_t)b * T_ + t] + s;
      }
    }
    __syncthreads();

    const int start = tc * 100;
    const float2* Eb = (const float2*)(a.enc + ((size_t)b * T_ + start) * INP) + tid;
    const float* su = &sm->s_u[start];
    float2 a0 = {0.f, 0.f}, a1 = {0.f, 0.f}, a2 = {0.f, 0.f}, a3 = {0.f, 0.f};
    for (int t = 0; t < 100; t += 4) {
      float s0 = su[t], s1 = su[t + 1], s2 = su[t + 2], s3 = su[t + 3];
      float2 e0 = Eb[(size_t)(t)     * 256];
      float2 e1 = Eb[(size_t)(t + 1) * 256];
      float2 e2 = Eb[(size_t)(t + 2) * 256];
      float2 e3 = Eb[(size_t)(t + 3) * 256];
      a0.x += s0 * e0.x; a0.y += s0 * e0.y;
      a1.x += s1 * e1.x; a1.y += s1 * e1.y;
      a2.x += s2 * e2.x; a2.y += s2 * e2.y;
      a3.x += s3 * e3.x; a3.y += s3 * e3.y;
    }
    float2 r;
    r.x = (a0.x + a1.x) + (a2.x + a3.x);
    r.y = (a0.y + a1.y) + (a2.y + a3.y);
    *(float2*)&a.ws_part[((size_t)tc * B_ + b) * INP + 2 * tid] = r;
    __syncthreads();
  }
}

__device__ void reduce_phase(const Args& a) {
  const int tid = threadIdx.x;
  for (int w = blockIdx.x; w < (B_ * INP) / 256; w += gridDim.x) {
    int idx = w * 256 + tid;
    int b = idx >> 9, d = idx & 511;
    float acc = 0.f;
#pragma unroll
    for (int tc = 0; tc < TCH; ++tc) acc += a.ws_part[((size_t)tc * B_ + b) * INP + d];
    a.o_ctx[idx] = acc;
  }
}

// ---------------------------------------------------------------------------
__device__ void cell_phase(
    const float* __restrict__ g4, const float* __restrict__ bih,
    const float* __restrict__ bhh, const float* __restrict__ c_old,
    const float* __restrict__ x_in,
    float* __restrict__ h_out, float* __restrict__ c_out, float* __restrict__ x_out)
{
  const size_t SEG = (size_t)B_ * 4096;
  const int tid = threadIdx.x;
  for (int w = blockIdx.x; w < (B_ * LSTM_) / 256; w += gridDim.x) {
    int idx = w * 256 + tid;
    int b = idx >> 10, j = idx & 1023;
    const float* gb = g4 + (size_t)b * 4096;
    float ig = gb[j]        + gb[SEG + j]        + gb[2*SEG + j]        + gb[3*SEG + j]        + bih[j]        + bhh[j];
    float fg = gb[1024 + j] + gb[SEG + 1024 + j] + gb[2*SEG + 1024 + j] + gb[3*SEG + 1024 + j] + bih[1024 + j] + bhh[1024 + j];
    float gg = gb[2048 + j] + gb[SEG + 2048 + j] + gb[2*SEG + 2048 + j] + gb[3*SEG + 2048 + j] + bih[2048 + j] + bhh[2048 + j];
    float og = gb[3072 + j] + gb[SEG + 3072 + j] + gb[2*SEG + 3072 + j] + gb[3*SEG + 3072 + j] + bih[3072 + j] + bhh[3072 + j];
    float cn = sigmoidf_(fg) * c_old[idx] + sigmoidf_(ig) * tanhf_(gg);
    float hn = sigmoidf_(og) * tanhf_(cn);
    h_out[idx] = hn;
    c_out[idx] = cn;
    x_out[idx] = x_in[idx] + hn;
  }
}

// ---------------------------------------------------------------------------
__device__ void mel_phase(const Args& a, char* smraw) {
  SmemMel* sm = (SmemMel*)smraw;
  const int tid = threadIdx.x;
  const int lane = tid & 63, wave = tid >> 6;
  for (int b = blockIdx.x; b < B_; b += gridDim.x) {
    __syncthreads();
    for (int k = tid; k < LSTM_; k += 256) sm->s_x[k] = a.ws_x3[(size_t)b * LSTM_ + k];
    for (int k = tid; k < INP; k += 256) sm->s_c[k] = a.o_ctx[(size_t)b * INP + k];
    __syncthreads();
#pragma unroll
    for (int i = 0; i < 20; ++i) {
      int n = wave * 20 + i;
      const float* wrow = a.melw + (size_t)n * MAXR * LSTM_;
      float acc = 0.f;
      for (int k = lane; k < LSTM_; k += 64) acc += sm->s_x[k] * wrow[k];
#pragma unroll
      for (int o = 32; o >= 1; o >>= 1) acc += __shfl_xor(acc, o);
      if (lane == 0) a.o_mels[(size_t)b * NMELS + n] = acc;
    }
    float p = 0.f;
    for (int k = tid; k < LSTM_; k += 256) p += sm->s_x[k] * a.stopw[k];
    for (int k = tid; k < INP; k += 256) p += sm->s_c[k] * a.stopw[LSTM_ + k];
#pragma unroll
    for (int o = 32; o >= 1; o >>= 1) p += __shfl_xor(p, o);
    if (lane == 0) sm->s_red[wave] = p;
    __syncthreads();
    if (tid == 0) {
      float t = sm->s_red[0] + sm->s_red[1] + sm->s_red[2] + sm->s_red[3] + a.stopb[0];
      a.o_stop[b] = sigmoidf_(t);
    }
    __syncthreads();
  }
}

// ---------------------------------------------------------------------------
// Persistent mega-kernel. __launch_bounds__(256, 4): VGPR capped at 128
// (512/4) -> 4 waves/SIMD (m69 halving) -> 4 blocks/CU with LDS 33KBx4<=160KB.
// ---------------------------------------------------------------------------
__global__ __launch_bounds__(256, 4) void mega_kernel(Args a) {
  __shared__ __align__(16) char smem[SMEM_BYTES];
  unsigned ep = 0;

  gemm_phase(a.prein, 80, a.pw1, 80, 80, nullptr, 0, nullptr, 0, 0,
             a.pb1, nullptr, a.ws_h, 256, 1, 0, 4, 4, 1, 256, smem);
  grid_bar(a.bar, ep);
  gemm_phase(a.ws_h, 256, a.pw2, 256, 256, nullptr, 0, nullptr, 0, 0,
             a.pb2, nullptr, a.ws_pre2, 256, 1, 0, 4, 4, 1, 256, smem);
  grid_bar(a.bar, ep);
  gemm_phase(a.ctx0, 512, a.gwih, 768, 512, a.ws_pre2, 256, a.gwih + 512, 768, 256,
             nullptr, nullptr, a.ws_gi2, 384, 0, 1, 6, 4, 2, 256, smem);
  grid_bar(a.bar, ep);
  gru_phase(a, smem);
  grid_bar(a.bar, ep);
  attn_phase(a, smem);
  grid_bar(a.bar, ep);
  ctx_phase(a, smem);
  grid_bar(a.bar, ep);
  reduce_phase(a);
  grid_bar(a.bar, ep);
  gemm_phase(a.o_ctx, 512, a.riw, 640, 512, a.o_attn, 128, a.riw + 512, 640, 128,
             a.rib, nullptr, a.ws_x, 1024, 0, 0, 16, 4, 1, 256, smem);
  grid_bar(a.bar, ep);
  gemm_phase(a.ws_x, 1024, a.l1wih, 1024, 1024, a.h1_0, 1024, a.l1whh, 1024, 1024,
             nullptr, nullptr, a.ws_g4, 4096, 0, 2, 64, 4, 4, 256, smem);
  grid_bar(a.bar, ep);
  cell_phase(a.ws_g4, a.l1bih, a.l1bhh, a.c1_0, a.ws_x, a.o_h1, a.o_c1, a.ws_x2);
  grid_bar(a.bar, ep);
  gemm_phase(a.ws_x2, 1024, a.l2wih, 1024, 1024, a.h2_0, 1024, a.l2whh, 1024, 1024,
             nullptr, nullptr, a.ws_g4, 4096, 0, 2, 64, 4, 4, 256, smem);
  grid_bar(a.bar, ep);
  cell_phase(a.ws_g4, a.l2bih, a.l2bhh, a.c2_0, a.ws_x2, a.o_h2, a.o_c2, a.ws_x3);
  grid_bar(a.bar, ep);
  mel_phase(a, smem);
}

// ---------------------------------------------------------------------------
extern "C" void kernel_launch(void* const* d_in, const int* in_sizes, int n_in,
                              void* d_out, int out_size, void* d_ws, size_t ws_size,
                              hipStream_t stream) {
  Args a;
  a.enc   = (const float*)d_in[0];
  a.esp   = (const float*)d_in[1];
  a.prein = (const float*)d_in[2];
  a.ah0   = (const float*)d_in[3];
  a.h1_0  = (const float*)d_in[4];
  a.h2_0  = (const float*)d_in[5];
  a.c1_0  = (const float*)d_in[6];
  a.c2_0  = (const float*)d_in[7];
  a.ctx0  = (const float*)d_in[8];
  a.cum   = (const float*)d_in[9];
  a.chars = (const int*)d_in[10];
  a.pw1 = (const float*)d_in[11];  a.pb1 = (const float*)d_in[12];
  a.pw2 = (const float*)d_in[13];  a.pb2 = (const float*)d_in[14];
  a.gwih = (const float*)d_in[15]; a.gwhh = (const float*)d_in[16];
  a.gbih = (const float*)d_in[17]; a.gbhh = (const float*)d_in[18];
  a.cvw = (const float*)d_in[19];  a.cvb = (const float*)d_in[20];
  a.lsaL = (const float*)d_in[21]; a.lsaW = (const float*)d_in[22];
  a.lsaWb = (const float*)d_in[23]; a.lsav = (const float*)d_in[24];
  a.riw = (const float*)d_in[25];  a.rib = (const float*)d_in[26];
  a.l1wih = (const float*)d_in[27]; a.l1whh = (const float*)d_in[28];
  a.l1bih = (const float*)d_in[29]; a.l1bhh = (const float*)d_in[30];
  a.l2wih = (const float*)d_in[31]; a.l2whh = (const float*)d_in[32];
  a.l2bih = (const float*)d_in[33]; a.l2bhh = (const float*)d_in[34];
  a.melw = (const float*)d_in[35]; a.stopw = (const float*)d_in[36];
  a.stopb = (const float*)d_in[37];

  float* out = (float*)d_out;
  a.o_mels   = out;
  a.o_scores = out + 20480;
  a.o_attn   = out + 122880;
  a.o_h1     = out + 155648;
  a.o_h2     = out + 417792;
  a.o_c1     = out + 679936;
  a.o_c2     = out + 942080;
  a.o_ctx    = out + 1204224;
  a.o_stop   = out + 1335296;
  a.o_cum    = out + 1335552;

  float* ws = (float*)d_ws;
  a.bar     = (unsigned*)ws;         // 64 floats reserved for barrier
  float* base = ws + 64;
  a.ws_h    = base;                  // 256*256
  a.ws_pre2 = base + 65536;          // 256*256
  a.ws_gi2  = base + 131072;         // 2*256*384
  a.ws_pq   = base + 327680;         // 256*128
  a.ws_u    = base + 360448;         // 256*400
  a.ws_part = base + 462848;         // 4*256*512
  a.ws_x    = base + 987136;         // 256*1024
  a.ws_x2   = base + 1249280;        // 256*1024
  a.ws_x3   = base + 1511424;        // 256*1024
  a.ws_g4   = base + 1773568;        // 4*256*4096

  // Grid sizing from MEASURED occupancy rules ONLY (m69 halving + LDS 160KB).
  // The occupancy API under-reports (assumes 64KB LDS budget) -- do not use.
  int per_cu = 4;   // by construction: __launch_bounds__(256,4) caps VGPR at 128
  hipFuncAttributes attr;
  if (hipFuncGetAttributes(&attr, (const void*)mega_kernel) == hipSuccess && attr.numRegs > 0) {
    int r = attr.numRegs;
    per_cu = (r <= 128) ? 4 : (r <= 256) ? 2 : 1;   // waves/SIMD at 4-wave blocks
  }
  if (per_cu > 4) per_cu = 4;        // LDS cap: 160KB / 33KB = 4
  int ncu = 256;
  (void)hipDeviceGetAttribute(&ncu, hipDeviceAttributeMultiprocessorCount, 0);
  int nblk = ncu * per_cu;
  if (nblk > 1024) nblk = 1024;

  (void)hipMemsetAsync(d_ws, 0, 256, stream);
  mega_kernel<<<dim3(nblk), dim3(256), 0, stream>>>(a);
}

// Round 13
// 364.697 us; speedup vs baseline: 4.4051x; 4.4051x over previous
//
#include <hip/hip_runtime.h>
#include <hip/hip_bf16.h>

#define B_ 256
#define T_ 400
#define NMELS 80
#define INP 512
#define DEC_ 128
#define LSTM_ 1024
#define FILT 32
#define KS 31
#define MAXR 20
#define TCH 2

typedef float f32x4 __attribute__((ext_vector_type(4)));
typedef short bf16x8 __attribute__((ext_vector_type(8)));

__device__ __forceinline__ short f2bf(float f) {
  union { float f; unsigned u; } v; v.f = f;
  unsigned u = v.u;
  unsigned r = (u + 0x7fffu + ((u >> 16) & 1u)) >> 16;
  return (short)r;
}

__device__ __forceinline__ bf16x8 pack8(float4 a0, float4 a1) {
  bf16x8 r;
  r[0] = f2bf(a0.x); r[1] = f2bf(a0.y); r[2] = f2bf(a0.z); r[3] = f2bf(a0.w);
  r[4] = f2bf(a1.x); r[5] = f2bf(a1.y); r[6] = f2bf(a1.z); r[7] = f2bf(a1.w);
  return r;
}

__device__ __forceinline__ float sigmoidf_(float x) {
  return 1.f / (1.f + __expf(-x));
}
__device__ __forceinline__ float tanhf_(float x) {
  float e = __expf(2.f * x);
  return 1.f - 2.f / (e + 1.f);
}

// ---------------------------------------------------------------------------
struct Args {
  const float *enc, *esp, *prein, *ah0, *h1_0, *h2_0, *c1_0, *c2_0, *ctx0, *cum;
  const int* chars;
  const float *pw1, *pb1, *pw2, *pb2;
  const float *gwih, *gwhh, *gbih, *gbhh;
  const float *cvw, *cvb, *lsaL, *lsaW, *lsaWb, *lsav;
  const float *riw, *rib;
  const float *l1wih, *l1whh, *l1bih, *l1bhh;
  const float *l2wih, *l2whh, *l2bih, *l2bhh;
  const float *melw, *stopw, *stopb;
  float *o_mels, *o_scores, *o_attn, *o_h1, *o_h2, *o_c1, *o_c2, *o_ctx, *o_stop, *o_cum;
  float *ws_pq, *ws_u, *ws_part, *ws_x, *ws_x2, *ws_g4;
};

// ---------------------------------------------------------------------------
// Fused head: prenet1 + prenet2 + gi + gh + GRU cell + processed_query.
// One block per batch row. Replaces 4 dispatches.
// ---------------------------------------------------------------------------
__global__ __launch_bounds__(256) void head_kernel(Args a) {
  __shared__ float s_x[768];    // [ctx | prenet_out]
  __shared__ float s_p[80];
  __shared__ float s_h1[256];
  __shared__ float s_hold[DEC_];
  __shared__ float s_gi[384];
  __shared__ float s_gh[384];
  __shared__ float s_h2[DEC_];
  const int b = blockIdx.x, tid = threadIdx.x;

  if (tid < 80)   s_p[tid]   = a.prein[(size_t)b * 80 + tid];
  if (tid < DEC_) s_hold[tid] = a.ah0[(size_t)b * DEC_ + tid];
  for (int i = tid; i < INP; i += 256) s_x[i] = a.ctx0[(size_t)b * INP + i];
  __syncthreads();

  // prenet1: h1 = relu(pw1 @ p + pb1)   (256 rows, K=80)
  {
    const float* w = a.pw1 + (size_t)tid * 80;
    float acc = a.pb1[tid];
#pragma unroll
    for (int k = 0; k < 80; k += 4)
      acc += w[k] * s_p[k] + w[k+1] * s_p[k+1] + w[k+2] * s_p[k+2] + w[k+3] * s_p[k+3];
    s_h1[tid] = fmaxf(acc, 0.f);
  }
  __syncthreads();

  // prenet2: x[512+tid] = relu(pw2 @ h1 + pb2)   (256 rows, K=256)
  {
    const float4* w = (const float4*)(a.pw2 + (size_t)tid * 256);
    float acc = a.pb2[tid];
#pragma unroll 8
    for (int q = 0; q < 64; ++q) {
      float4 wv = w[q];
      acc += wv.x * s_h1[q*4] + wv.y * s_h1[q*4+1] + wv.z * s_h1[q*4+2] + wv.w * s_h1[q*4+3];
    }
    s_x[INP + tid] = fmaxf(acc, 0.f);
  }
  __syncthreads();

  // gi = gwih @ [ctx | prenet] + gbih   (384 rows, K=768)
  for (int n = tid; n < 384; n += 256) {
    const float4* w = (const float4*)(a.gwih + (size_t)n * 768);
    float acc = a.gbih[n];
#pragma unroll 8
    for (int q = 0; q < 192; ++q) {
      float4 wv = w[q];
      acc += wv.x * s_x[q*4] + wv.y * s_x[q*4+1] + wv.z * s_x[q*4+2] + wv.w * s_x[q*4+3];
    }
    s_gi[n] = acc;
  }
  // gh = gwhh @ h_old + gbhh   (384 rows, K=128)
  for (int n = tid; n < 384; n += 256) {
    const float4* w = (const float4*)(a.gwhh + (size_t)n * DEC_);
    float acc = a.gbhh[n];
#pragma unroll
    for (int q = 0; q < 32; ++q) {
      float4 wv = w[q];
      acc += wv.x * s_hold[q*4] + wv.y * s_hold[q*4+1] + wv.z * s_hold[q*4+2] + wv.w * s_hold[q*4+3];
    }
    s_gh[n] = acc;
  }
  __syncthreads();

  // GRU cell
  if (tid < DEC_) {
    float r = sigmoidf_(s_gi[tid] + s_gh[tid]);
    float z = sigmoidf_(s_gi[128 + tid] + s_gh[128 + tid]);
    float n = tanhf_(s_gi[256 + tid] + r * s_gh[256 + tid]);
    float h = (1.f - z) * n + z * s_hold[tid];
    s_h2[tid] = h;
    a.o_attn[(size_t)b * DEC_ + tid] = h;
  }
  __syncthreads();

  // processed_query = lsaW @ h_new + lsaWb   (128 rows, K=128)
  if (tid < DEC_) {
    const float4* w = (const float4*)(a.lsaW + (size_t)tid * DEC_);
    float acc = a.lsaWb[tid];
#pragma unroll
    for (int q = 0; q < 32; ++q) {
      float4 wv = w[q];
      acc += wv.x * s_h2[q*4] + wv.y * s_h2[q*4+1] + wv.z * s_h2[q*4+2] + wv.w * s_h2[q*4+3];
    }
    a.ws_pq[(size_t)b * DEC_ + tid] = acc;
  }
}

// ---------------------------------------------------------------------------
// Attention scores via MFMA (R3-proven). Block (half, b): 200 t's.
// ---------------------------------------------------------------------------
__global__ __launch_bounds__(256) void attn_score_kernel(Args a) {
  __shared__ float s_cum[232];
  __shared__ __align__(16) short s_conv[208][40];
  __shared__ __align__(16) short s_L[128][40];
  __shared__ float s_w[FILT * KS];
  __shared__ float s_cb[FILT];
  __shared__ float s_pq[DEC_];
  __shared__ float s_v[DEC_];

  const int half = blockIdx.x;
  const int b    = blockIdx.y;
  const int tid  = threadIdx.x;
  const int t0   = half * 200;

  for (int i = tid; i < 230; i += 256) {
    int t = t0 - 15 + i;
    s_cum[i] = (t >= 0 && t < T_) ? a.cum[(size_t)b * T_ + t] : 0.f;
  }
  for (int i = tid; i < FILT * KS; i += 256) s_w[i] = a.cvw[i];
  for (int i = tid; i < DEC_ * FILT; i += 256) s_L[i >> 5][i & 31] = f2bf(a.lsaL[i]);
  if (tid < FILT) s_cb[tid] = a.cvb[tid];
  if (tid < DEC_) { s_pq[tid] = a.ws_pq[(size_t)b * DEC_ + tid]; s_v[tid] = a.lsav[tid]; }
  s_conv[200 + (tid >> 5)][tid & 31] = 0;
  __syncthreads();

  if (tid < 200) {
    float c[KS];
#pragma unroll
    for (int k = 0; k < KS; ++k) c[k] = s_cum[tid + k];
#pragma unroll
    for (int f = 0; f < FILT; ++f) {
      float acc = s_cb[f];
#pragma unroll
      for (int k = 0; k < KS; ++k) acc += c[k] * s_w[f * KS + k];
      s_conv[tid][f] = f2bf(acc);
    }
  }
  __syncthreads();

  const int lane = tid & 63, wave = tid >> 6;
  const int l15 = lane & 15, kq = (lane >> 4) * 8;
  for (int m = wave; m < 13; m += 4) {
    bf16x8 af = *(const bf16x8*)&s_conv[m * 16 + l15][kq];
    f32x4 acc[8];
#pragma unroll
    for (int n = 0; n < 8; ++n) {
      bf16x8 bf = *(const bf16x8*)&s_L[n * 16 + l15][kq];
      acc[n] = __builtin_amdgcn_mfma_f32_16x16x32_bf16(af, bf, (f32x4){0.f, 0.f, 0.f, 0.f}, 0, 0, 0);
    }
    const int trow = m * 16 + (lane >> 4) * 4;
    float u[4] = {0.f, 0.f, 0.f, 0.f};
#pragma unroll
    for (int n = 0; n < 8; ++n) {
      int d = n * 16 + l15;
      float pqd = s_pq[d], vd = s_v[d];
#pragma unroll
      for (int r = 0; r < 4; ++r) {
        int tl = trow + r;
        if (tl < 200) {
          float x = acc[n][r] + pqd + a.esp[((size_t)b * T_ + t0 + tl) * DEC_ + d];
          u[r] += tanhf_(x) * vd;
        }
      }
    }
#pragma unroll
    for (int r = 0; r < 4; ++r) {
#pragma unroll
      for (int o = 1; o < 16; o <<= 1) u[r] += __shfl_xor(u[r], o);
    }
    if (l15 == 0) {
#pragma unroll
      for (int r = 0; r < 4; ++r) {
        int tl = trow + r;
        if (tl < 200) {
          int t = t0 + tl;
          float uu = u[r];
          if (a.chars[(size_t)b * T_ + t] == 0) uu = 0.f;
          a.ws_u[(size_t)b * T_ + t] = uu;
        }
      }
    }
  }
}

// ---------------------------------------------------------------------------
// Softmax (redundant per tc) + context partial over 200-t chunk. Block (tc,b).
// ---------------------------------------------------------------------------
__global__ __launch_bounds__(256) void ctx_smax_part_kernel(Args a) {
  __shared__ float s_u[T_];
  __shared__ float s_red[8];
  const int tc = blockIdx.x, b = blockIdx.y, tid = threadIdx.x;
  const int lane = tid & 63, wave = tid >> 6;

  float mx = -1e30f;
  for (int t = tid; t < T_; t += 256) {
    float v = a.ws_u[(size_t)b * T_ + t];
    s_u[t] = v;
    mx = fmaxf(mx, v);
  }
#pragma unroll
  for (int o = 32; o >= 1; o >>= 1) mx = fmaxf(mx, __shfl_xor(mx, o));
  if (lane == 0) s_red[wave] = mx;
  __syncthreads();
  mx = fmaxf(fmaxf(s_red[0], s_red[1]), fmaxf(s_red[2], s_red[3]));

  float smv = 0.f;
  for (int t = tid; t < T_; t += 256) {
    float e = __expf(s_u[t] - mx);
    s_u[t] = e;
    smv += e;
  }
#pragma unroll
  for (int o = 32; o >= 1; o >>= 1) smv += __shfl_xor(smv, o);
  if (lane == 0) s_red[4 + wave] = smv;
  __syncthreads();
  smv = s_red[4] + s_red[5] + s_red[6] + s_red[7];
  float inv = 1.f / smv;
  for (int t = tid; t < T_; t += 256) {
    float s = s_u[t] * inv;
    s_u[t] = s;
    if (tc == 0) {
      a.o_scores[(size_t)b * T_ + t] = s;
      a.o_cum[(size_t)b * T_ + t] = a.cum[(size_t)b * T_ + t] + s;
    }
  }
  __syncthreads();

  const int start = tc * 200;
  const float2* Eb = (const float2*)(a.enc + ((size_t)b * T_ + start) * INP) + tid;
  const float* su = &s_u[start];
  float2 a0 = {0.f, 0.f}, a1 = {0.f, 0.f}, a2 = {0.f, 0.f}, a3 = {0.f, 0.f};
  for (int t = 0; t < 200; t += 4) {
    float s0 = su[t], s1 = su[t + 1], s2 = su[t + 2], s3 = su[t + 3];
    float2 e0 = Eb[(size_t)(t)     * 256];
    float2 e1 = Eb[(size_t)(t + 1) * 256];
    float2 e2 = Eb[(size_t)(t + 2) * 256];
    float2 e3 = Eb[(size_t)(t + 3) * 256];
    a0.x += s0 * e0.x; a0.y += s0 * e0.y;
    a1.x += s1 * e1.x; a1.y += s1 * e1.y;
    a2.x += s2 * e2.x; a2.y += s2 * e2.y;
    a3.x += s3 * e3.x; a3.y += s3 * e3.y;
  }
  float2 r;
  r.x = (a0.x + a1.x) + (a2.x + a3.x);
  r.y = (a0.y + a1.y) + (a2.y + a3.y);
  *(float2*)&a.ws_part[((size_t)tc * B_ + b) * INP + 2 * tid] = r;
}

// ---------------------------------------------------------------------------
// Generic bf16-MFMA GEMM (R3-proven) + optional A1-partial-sum staging mode:
// if A1b != nullptr, A = A1 + A1b (elementwise); if ctx_side != nullptr,
// the summed A is also written there (redundantly across bn tiles, benign).
// zmode: 0 = full (bias); 2 = blockIdx.z = pair*2 + K-half (partials).
// ---------------------------------------------------------------------------
__global__ __launch_bounds__(256) void gemm_bf16(
    const float* __restrict__ A1, const float* __restrict__ A1b,
    float* __restrict__ ctx_side, int lda1,
    const float* __restrict__ W1, int ldw1, int K1,
    const float* __restrict__ A2, int lda2, const float* __restrict__ W2, int ldw2, int K2,
    const float* __restrict__ bias1, const float* __restrict__ bias2,
    float* __restrict__ out, int ldo, int act, int zmode)
{
  __shared__ __align__(16) short sA[64][40];
  __shared__ __align__(16) short sB[64][40];
  const int tid  = threadIdx.x;
  const int lane = tid & 63;
  const int wave = tid >> 6;
  const int wr = (wave >> 1) * 32;
  const int wc = (wave & 1) * 32;
  const int bm = blockIdx.y * 64;
  const int bn = blockIdx.x * 64;
  const int sr = tid >> 2;
  const int sk = (tid & 3) * 8;
  const int l15 = lane & 15;
  const int kq  = (lane >> 4) * 8;

  int kb1 = 0, ke1 = K1, kb2 = 0, ke2 = K2;
  if (zmode == 2) {
    int p = blockIdx.z >> 1, h = blockIdx.z & 1;
    if (p == 0) { ke2 = 0; int half = K1 >> 1; kb1 = h * half; ke1 = kb1 + half; }
    else        { ke1 = 0; int half = K2 >> 1; kb2 = h * half; ke2 = kb2 + half; }
  }
  float* outp = out;
  if (zmode == 2) outp += (size_t)blockIdx.z * (size_t)(gridDim.y * 64) * ldo;

  f32x4 acc[2][2];
#pragma unroll
  for (int i = 0; i < 2; ++i)
#pragma unroll
    for (int j = 0; j < 2; ++j) acc[i][j] = (f32x4){0.f, 0.f, 0.f, 0.f};

  for (int pair = 0; pair < 2; ++pair) {
    const int kb = pair ? kb2 : kb1;
    const int ke = pair ? ke2 : ke1;
    if (ke <= kb) continue;
    const float* A = pair ? A2 : A1;
    const float* Ab = pair ? nullptr : A1b;
    const float* W = pair ? W2 : W1;
    const int lda = pair ? lda2 : lda1;
    const int ldw = pair ? ldw2 : ldw1;
    const float* arow  = A + (size_t)(bm + sr) * lda;
    const float* arowb = Ab ? Ab + (size_t)(bm + sr) * lda : nullptr;
    const float* wrow  = W + (size_t)(bn + sr) * ldw;
    float* crow = (pair == 0 && ctx_side) ? ctx_side + (size_t)(bm + sr) * lda : nullptr;

    float4 ra0, ra1, rb0, rb1;
    if (kb + 32 <= ke) {
      const float* pa = arow + kb + sk;
      const float* pw = wrow + kb + sk;
      ra0 = *(const float4*)pa; ra1 = *(const float4*)(pa + 4);
      if (arowb) {
        const float* pb = arowb + kb + sk;
        float4 b0 = *(const float4*)pb, b1 = *(const float4*)(pb + 4);
        ra0.x += b0.x; ra0.y += b0.y; ra0.z += b0.z; ra0.w += b0.w;
        ra1.x += b1.x; ra1.y += b1.y; ra1.z += b1.z; ra1.w += b1.w;
      }
      rb0 = *(const float4*)pw; rb1 = *(const float4*)(pw + 4);
    }
    for (int k0 = kb; k0 < ke; k0 += 32) {
      __syncthreads();
      if (k0 + 32 <= ke) {
        *(bf16x8*)&sA[sr][sk] = pack8(ra0, ra1);
        *(bf16x8*)&sB[sr][sk] = pack8(rb0, rb1);
        if (crow) {
          *(float4*)(crow + k0 + sk) = ra0;
          *(float4*)(crow + k0 + sk + 4) = ra1;
        }
        if (k0 + 64 <= ke) {
          const float* pa = arow + k0 + 32 + sk;
          const float* pw = wrow + k0 + 32 + sk;
          ra0 = *(const float4*)pa; ra1 = *(const float4*)(pa + 4);
          if (arowb) {
            const float* pb = arowb + k0 + 32 + sk;
            float4 b0 = *(const float4*)pb, b1 = *(const float4*)(pb + 4);
            ra0.x += b0.x; ra0.y += b0.y; ra0.z += b0.z; ra0.w += b0.w;
            ra1.x += b1.x; ra1.y += b1.y; ra1.z += b1.z; ra1.w += b1.w;
          }
          rb0 = *(const float4*)pw; rb1 = *(const float4*)(pw + 4);
        }
      } else {   // K tail (unused: all K multiples of 32)
        short* da = &sA[sr][sk];
        short* db = &sB[sr][sk];
#pragma unroll
        for (int j = 0; j < 8; ++j) {
          int k = k0 + sk + j;
          float av = (k < ke) ? arow[k] + (arowb ? arowb[k] : 0.f) : 0.f;
          da[j] = (k < ke) ? f2bf(av) : (short)0;
          db[j] = (k < ke) ? f2bf(wrow[k]) : (short)0;
        }
      }
      __syncthreads();
      bf16x8 af[2], bfv[2];
      af[0]  = *(const bf16x8*)&sA[wr + l15][kq];
      af[1]  = *(const bf16x8*)&sA[wr + 16 + l15][kq];
      bfv[0] = *(const bf16x8*)&sB[wc + l15][kq];
      bfv[1] = *(const bf16x8*)&sB[wc + 16 + l15][kq];
#pragma unroll
      for (int i = 0; i < 2; ++i)
#pragma unroll
        for (int j = 0; j < 2; ++j)
          acc[i][j] = __builtin_amdgcn_mfma_f32_16x16x32_bf16(af[i], bfv[j], acc[i][j], 0, 0, 0);
    }
  }

#pragma unroll
  for (int i = 0; i < 2; ++i) {
#pragma unroll
    for (int j = 0; j < 2; ++j) {
      int n = bn + wc + j * 16 + l15;
      float bv = 0.f;
      if (zmode == 0) bv = (bias1 ? bias1[n] : 0.f) + (bias2 ? bias2[n] : 0.f);
#pragma unroll
      for (int r = 0; r < 4; ++r) {
        int m = bm + wr + i * 16 + (lane >> 4) * 4 + r;
        float v = acc[i][j][r] + bv;
        if (act == 1) v = fmaxf(v, 0.f);
        outp[(size_t)m * ldo + n] = v;
      }
    }
  }
}

// ---------------------------------------------------------------------------
// LSTM cell (4 gate partials) + residual (R3-proven).
// ---------------------------------------------------------------------------
__global__ __launch_bounds__(256) void lstm_cell_kernel(
    const float* __restrict__ g4, const float* __restrict__ bih,
    const float* __restrict__ bhh, const float* __restrict__ c_old,
    const float* __restrict__ x_in,
    float* __restrict__ h_out, float* __restrict__ c_out,
    float* __restrict__ x_out)
{
  const size_t SEG = (size_t)B_ * 4096;
  int idx = blockIdx.x * 256 + threadIdx.x;
  if (idx >= B_ * LSTM_) return;
  int b = idx >> 10, j = idx & 1023;
  const float* gb = g4 + (size_t)b * 4096;
  float ig = gb[j]        + gb[SEG + j]        + gb[2*SEG + j]        + gb[3*SEG + j]        + bih[j]        + bhh[j];
  float fg = gb[1024 + j] + gb[SEG + 1024 + j] + gb[2*SEG + 1024 + j] + gb[3*SEG + 1024 + j] + bih[1024 + j] + bhh[1024 + j];
  float gg = gb[2048 + j] + gb[SEG + 2048 + j] + gb[2*SEG + 2048 + j] + gb[3*SEG + 2048 + j] + bih[2048 + j] + bhh[2048 + j];
  float og = gb[3072 + j] + gb[SEG + 3072 + j] + gb[2*SEG + 3072 + j] + gb[3*SEG + 3072 + j] + bih[3072 + j] + bhh[3072 + j];
  float cn = sigmoidf_(fg) * c_old[idx] + sigmoidf_(ig) * tanhf_(gg);
  float hn = sigmoidf_(og) * tanhf_(cn);
  h_out[idx] = hn;
  c_out[idx] = cn;
  x_out[idx] = x_in[idx] + hn;
}

// ---------------------------------------------------------------------------
// Fused cell2 + mel head + stop head. One block per batch row.
// ---------------------------------------------------------------------------
__global__ __launch_bounds__(256) void mel_cell_kernel(Args a) {
  __shared__ float s_x[LSTM_];
  __shared__ float s_c[INP];
  __shared__ float s_red[4];
  const int b = blockIdx.x, tid = threadIdx.x;
  const int lane = tid & 63, wave = tid >> 6;
  const size_t SEG = (size_t)B_ * 4096;

  // cell2 for this row: gates -> h2,c2 (d_out) and x3 = x2 + h2 in LDS
  for (int j = tid; j < LSTM_; j += 256) {
    const float* gb = a.ws_g4 + (size_t)b * 4096;
    float ig = gb[j]        + gb[SEG + j]        + gb[2*SEG + j]        + gb[3*SEG + j]        + a.l2bih[j]        + a.l2bhh[j];
    float fg = gb[1024 + j] + gb[SEG + 1024 + j] + gb[2*SEG + 1024 + j] + gb[3*SEG + 1024 + j] + a.l2bih[1024 + j] + a.l2bhh[1024 + j];
    float gg = gb[2048 + j] + gb[SEG + 2048 + j] + gb[2*SEG + 2048 + j] + gb[3*SEG + 2048 + j] + a.l2bih[2048 + j] + a.l2bhh[2048 + j];
    float og = gb[3072 + j] + gb[SEG + 3072 + j] + gb[2*SEG + 3072 + j] + gb[3*SEG + 3072 + j] + a.l2bih[3072 + j] + a.l2bhh[3072 + j];
    size_t idx = (size_t)b * LSTM_ + j;
    float cn = sigmoidf_(fg) * a.c2_0[idx] + sigmoidf_(ig) * tanhf_(gg);
    float hn = sigmoidf_(og) * tanhf_(cn);
    a.o_h2[idx] = hn;
    a.o_c2[idx] = cn;
    s_x[j] = a.ws_x2[idx] + hn;
  }
  for (int k = tid; k < INP; k += 256) s_c[k] = a.o_ctx[(size_t)b * INP + k];
  __syncthreads();

#pragma unroll
  for (int i = 0; i < 20; ++i) {
    int n = wave * 20 + i;
    const float* wrow = a.melw + (size_t)n * MAXR * LSTM_;
    float acc = 0.f;
    for (int k = lane; k < LSTM_; k += 64) acc += s_x[k] * wrow[k];
#pragma unroll
    for (int o = 32; o >= 1; o >>= 1) acc += __shfl_xor(acc, o);
    if (lane == 0) a.o_mels[(size_t)b * NMELS + n] = acc;
  }
  float p = 0.f;
  for (int k = tid; k < LSTM_; k += 256) p += s_x[k] * a.stopw[k];
  for (int k = tid; k < INP; k += 256) p += s_c[k] * a.stopw[LSTM_ + k];
#pragma unroll
  for (int o = 32; o >= 1; o >>= 1) p += __shfl_xor(p, o);
  if (lane == 0) s_red[wave] = p;
  __syncthreads();
  if (tid == 0) {
    float t = s_red[0] + s_red[1] + s_red[2] + s_red[3] + a.stopb[0];
    a.o_stop[b] = sigmoidf_(t);
  }
}

// ---------------------------------------------------------------------------
extern "C" void kernel_launch(void* const* d_in, const int* in_sizes, int n_in,
                              void* d_out, int out_size, void* d_ws, size_t ws_size,
                              hipStream_t stream) {
  Args a;
  a.enc   = (const float*)d_in[0];
  a.esp   = (const float*)d_in[1];
  a.prein = (const float*)d_in[2];
  a.ah0   = (const float*)d_in[3];
  a.h1_0  = (const float*)d_in[4];
  a.h2_0  = (const float*)d_in[5];
  a.c1_0  = (const float*)d_in[6];
  a.c2_0  = (const float*)d_in[7];
  a.ctx0  = (const float*)d_in[8];
  a.cum   = (const float*)d_in[9];
  a.chars = (const int*)d_in[10];
  a.pw1 = (const float*)d_in[11];  a.pb1 = (const float*)d_in[12];
  a.pw2 = (const float*)d_in[13];  a.pb2 = (const float*)d_in[14];
  a.gwih = (const float*)d_in[15]; a.gwhh = (const float*)d_in[16];
  a.gbih = (const float*)d_in[17]; a.gbhh = (const float*)d_in[18];
  a.cvw = (const float*)d_in[19];  a.cvb = (const float*)d_in[20];
  a.lsaL = (const float*)d_in[21]; a.lsaW = (const float*)d_in[22];
  a.lsaWb = (const float*)d_in[23]; a.lsav = (const float*)d_in[24];
  a.riw = (const float*)d_in[25];  a.rib = (const float*)d_in[26];
  a.l1wih = (const float*)d_in[27]; a.l1whh = (const float*)d_in[28];
  a.l1bih = (const float*)d_in[29]; a.l1bhh = (const float*)d_in[30];
  a.l2wih = (const float*)d_in[31]; a.l2whh = (const float*)d_in[32];
  a.l2bih = (const float*)d_in[33]; a.l2bhh = (const float*)d_in[34];
  a.melw = (const float*)d_in[35]; a.stopw = (const float*)d_in[36];
  a.stopb = (const float*)d_in[37];

  float* out = (float*)d_out;
  a.o_mels   = out;
  a.o_scores = out + 20480;
  a.o_attn   = out + 122880;
  a.o_h1     = out + 155648;
  a.o_h2     = out + 417792;
  a.o_c1     = out + 679936;
  a.o_c2     = out + 942080;
  a.o_ctx    = out + 1204224;
  a.o_stop   = out + 1335296;
  a.o_cum    = out + 1335552;

  float* ws = (float*)d_ws;
  a.ws_pq   = ws;                    // 256*128           = 32768
  a.ws_u    = ws + 32768;            // 256*400           = 102400
  a.ws_part = ws + 135168;           // 2*256*512         = 262144
  a.ws_x    = ws + 397312;           // 256*1024          = 262144
  a.ws_x2   = ws + 659456;           // 256*1024          = 262144
  a.ws_g4   = ws + 921600;           // 4*256*4096        = 4194304

  dim3 blk(256);

  // 1. fused head: prenet1+prenet2+gi+gh+GRU+pq
  head_kernel<<<dim3(B_), blk, 0, stream>>>(a);
  // 2. attention scores (MFMA)
  attn_score_kernel<<<dim3(2, B_), blk, 0, stream>>>(a);
  // 3. softmax + context partials (TCH=2)
  ctx_smax_part_kernel<<<dim3(TCH, B_), blk, 0, stream>>>(a);
  // 4. rnn_in = [ctx | attn_hidden] @ riw^T + rib, with ctx = part0+part1
  //    summed in staging; o_ctx side-written.
  gemm_bf16<<<dim3(16, 4, 1), blk, 0, stream>>>(
      a.ws_part, a.ws_part + (size_t)B_ * INP, a.o_ctx, 512,
      a.riw, 640, 512,
      a.o_attn, 128, a.riw + 512, 640, 128,
      a.rib, nullptr, a.ws_x, 1024, 0, 0);
  // 5. LSTM1 gates (K-split partials)
  gemm_bf16<<<dim3(64, 4, 4), blk, 0, stream>>>(
      a.ws_x, nullptr, nullptr, 1024, a.l1wih, 1024, 1024,
      a.h1_0, 1024, a.l1whh, 1024, 1024,
      nullptr, nullptr, a.ws_g4, 4096, 0, 2);
  // 6. LSTM1 cell -> h1,c1 (d_out); x2 = x + h1
  lstm_cell_kernel<<<dim3(1024), blk, 0, stream>>>(
      a.ws_g4, a.l1bih, a.l1bhh, a.c1_0, a.ws_x, a.o_h1, a.o_c1, a.ws_x2);
  // 7. LSTM2 gates
  gemm_bf16<<<dim3(64, 4, 4), blk, 0, stream>>>(
      a.ws_x2, nullptr, nullptr, 1024, a.l2wih, 1024, 1024,
      a.h2_0, 1024, a.l2whh, 1024, 1024,
      nullptr, nullptr, a.ws_g4, 4096, 0, 2);
  // 8. cell2 + mel + stop
  mel_cell_kernel<<<dim3(B_), blk, 0, stream>>>(a);
}

// Round 14
// 271.111 us; speedup vs baseline: 5.9257x; 1.3452x over previous
//
#include <hip/hip_runtime.h>
#include <hip/hip_bf16.h>

#define B_ 256
#define T_ 400
#define NMELS 80
#define INP 512
#define DEC_ 128
#define LSTM_ 1024
#define FILT 32
#define KS 31
#define MAXR 20
#define TCH 2

typedef float f32x4 __attribute__((ext_vector_type(4)));
typedef short bf16x8 __attribute__((ext_vector_type(8)));

__device__ __forceinline__ short f2bf(float f) {
  union { float f; unsigned u; } v; v.f = f;
  unsigned u = v.u;
  unsigned r = (u + 0x7fffu + ((u >> 16) & 1u)) >> 16;
  return (short)r;
}

__device__ __forceinline__ bf16x8 pack8(float4 a0, float4 a1) {
  bf16x8 r;
  r[0] = f2bf(a0.x); r[1] = f2bf(a0.y); r[2] = f2bf(a0.z); r[3] = f2bf(a0.w);
  r[4] = f2bf(a1.x); r[5] = f2bf(a1.y); r[6] = f2bf(a1.z); r[7] = f2bf(a1.w);
  return r;
}

__device__ __forceinline__ float sigmoidf_(float x) {
  return 1.f / (1.f + __expf(-x));
}
__device__ __forceinline__ float tanhf_(float x) {
  float e = __expf(2.f * x);
  return 1.f - 2.f / (e + 1.f);
}

// ---------------------------------------------------------------------------
struct Args {
  const float *enc, *esp, *prein, *ah0, *h1_0, *h2_0, *c1_0, *c2_0, *ctx0, *cum;
  const int* chars;
  const float *pw1, *pb1, *pw2, *pb2;
  const float *gwih, *gwhh, *gbih, *gbhh;
  const float *cvw, *cvb, *lsaL, *lsaW, *lsaWb, *lsav;
  const float *riw, *rib;
  const float *l1wih, *l1whh, *l1bih, *l1bhh;
  const float *l2wih, *l2whh, *l2bih, *l2bhh;
  const float *melw, *stopw, *stopb;
  float *o_mels, *o_scores, *o_attn, *o_h1, *o_h2, *o_c1, *o_c2, *o_ctx, *o_stop, *o_cum;
  float *ws_pq, *ws_u, *ws_part, *ws_x, *ws_x2, *ws_g4;
};

// ---------------------------------------------------------------------------
// Fused head: prenet1 + prenet2 + gi + gh + GRU cell + processed_query.
// ---------------------------------------------------------------------------
__global__ __launch_bounds__(256) void head_kernel(Args a) {
  __shared__ float s_x[768];    // [ctx | prenet_out]
  __shared__ float s_p[80];
  __shared__ float s_h1[256];
  __shared__ float s_hold[DEC_];
  __shared__ float s_gi[384];
  __shared__ float s_gh[384];
  __shared__ float s_h2[DEC_];
  const int b = blockIdx.x, tid = threadIdx.x;

  if (tid < 80)   s_p[tid]   = a.prein[(size_t)b * 80 + tid];
  if (tid < DEC_) s_hold[tid] = a.ah0[(size_t)b * DEC_ + tid];
  for (int i = tid; i < INP; i += 256) s_x[i] = a.ctx0[(size_t)b * INP + i];
  __syncthreads();

  {
    const float* w = a.pw1 + (size_t)tid * 80;
    float acc = a.pb1[tid];
#pragma unroll
    for (int k = 0; k < 80; k += 4)
      acc += w[k] * s_p[k] + w[k+1] * s_p[k+1] + w[k+2] * s_p[k+2] + w[k+3] * s_p[k+3];
    s_h1[tid] = fmaxf(acc, 0.f);
  }
  __syncthreads();

  {
    const float4* w = (const float4*)(a.pw2 + (size_t)tid * 256);
    float acc = a.pb2[tid];
#pragma unroll 8
    for (int q = 0; q < 64; ++q) {
      float4 wv = w[q];
      acc += wv.x * s_h1[q*4] + wv.y * s_h1[q*4+1] + wv.z * s_h1[q*4+2] + wv.w * s_h1[q*4+3];
    }
    s_x[INP + tid] = fmaxf(acc, 0.f);
  }
  __syncthreads();

  for (int n = tid; n < 384; n += 256) {
    const float4* w = (const float4*)(a.gwih + (size_t)n * 768);
    float acc = a.gbih[n];
#pragma unroll 8
    for (int q = 0; q < 192; ++q) {
      float4 wv = w[q];
      acc += wv.x * s_x[q*4] + wv.y * s_x[q*4+1] + wv.z * s_x[q*4+2] + wv.w * s_x[q*4+3];
    }
    s_gi[n] = acc;
  }
  for (int n = tid; n < 384; n += 256) {
    const float4* w = (const float4*)(a.gwhh + (size_t)n * DEC_);
    float acc = a.gbhh[n];
#pragma unroll
    for (int q = 0; q < 32; ++q) {
      float4 wv = w[q];
      acc += wv.x * s_hold[q*4] + wv.y * s_hold[q*4+1] + wv.z * s_hold[q*4+2] + wv.w * s_hold[q*4+3];
    }
    s_gh[n] = acc;
  }
  __syncthreads();

  if (tid < DEC_) {
    float r = sigmoidf_(s_gi[tid] + s_gh[tid]);
    float z = sigmoidf_(s_gi[128 + tid] + s_gh[128 + tid]);
    float n = tanhf_(s_gi[256 + tid] + r * s_gh[256 + tid]);
    float h = (1.f - z) * n + z * s_hold[tid];
    s_h2[tid] = h;
    a.o_attn[(size_t)b * DEC_ + tid] = h;
  }
  __syncthreads();

  if (tid < DEC_) {
    const float4* w = (const float4*)(a.lsaW + (size_t)tid * DEC_);
    float acc = a.lsaWb[tid];
#pragma unroll
    for (int q = 0; q < 32; ++q) {
      float4 wv = w[q];
      acc += wv.x * s_h2[q*4] + wv.y * s_h2[q*4+1] + wv.z * s_h2[q*4+2] + wv.w * s_h2[q*4+3];
    }
    a.ws_pq[(size_t)b * DEC_ + tid] = acc;
  }
}

// ---------------------------------------------------------------------------
// Attention scores via MFMA (R3-proven). Block (half, b): 200 t's.
// ---------------------------------------------------------------------------
__global__ __launch_bounds__(256) void attn_score_kernel(Args a) {
  __shared__ float s_cum[232];
  __shared__ __align__(16) short s_conv[208][40];
  __shared__ __align__(16) short s_L[128][40];
  __shared__ float s_w[FILT * KS];
  __shared__ float s_cb[FILT];
  __shared__ float s_pq[DEC_];
  __shared__ float s_v[DEC_];

  const int half = blockIdx.x;
  const int b    = blockIdx.y;
  const int tid  = threadIdx.x;
  const int t0   = half * 200;

  for (int i = tid; i < 230; i += 256) {
    int t = t0 - 15 + i;
    s_cum[i] = (t >= 0 && t < T_) ? a.cum[(size_t)b * T_ + t] : 0.f;
  }
  for (int i = tid; i < FILT * KS; i += 256) s_w[i] = a.cvw[i];
  for (int i = tid; i < DEC_ * FILT; i += 256) s_L[i >> 5][i & 31] = f2bf(a.lsaL[i]);
  if (tid < FILT) s_cb[tid] = a.cvb[tid];
  if (tid < DEC_) { s_pq[tid] = a.ws_pq[(size_t)b * DEC_ + tid]; s_v[tid] = a.lsav[tid]; }
  s_conv[200 + (tid >> 5)][tid & 31] = 0;
  __syncthreads();

  if (tid < 200) {
    float c[KS];
#pragma unroll
    for (int k = 0; k < KS; ++k) c[k] = s_cum[tid + k];
#pragma unroll
    for (int f = 0; f < FILT; ++f) {
      float acc = s_cb[f];
#pragma unroll
      for (int k = 0; k < KS; ++k) acc += c[k] * s_w[f * KS + k];
      s_conv[tid][f] = f2bf(acc);
    }
  }
  __syncthreads();

  const int lane = tid & 63, wave = tid >> 6;
  const int l15 = lane & 15, kq = (lane >> 4) * 8;
  for (int m = wave; m < 13; m += 4) {
    bf16x8 af = *(const bf16x8*)&s_conv[m * 16 + l15][kq];
    f32x4 acc[8];
#pragma unroll
    for (int n = 0; n < 8; ++n) {
      bf16x8 bf = *(const bf16x8*)&s_L[n * 16 + l15][kq];
      acc[n] = __builtin_amdgcn_mfma_f32_16x16x32_bf16(af, bf, (f32x4){0.f, 0.f, 0.f, 0.f}, 0, 0, 0);
    }
    const int trow = m * 16 + (lane >> 4) * 4;
    float u[4] = {0.f, 0.f, 0.f, 0.f};
#pragma unroll
    for (int n = 0; n < 8; ++n) {
      int d = n * 16 + l15;
      float pqd = s_pq[d], vd = s_v[d];
#pragma unroll
      for (int r = 0; r < 4; ++r) {
        int tl = trow + r;
        if (tl < 200) {
          float x = acc[n][r] + pqd + a.esp[((size_t)b * T_ + t0 + tl) * DEC_ + d];
          u[r] += tanhf_(x) * vd;
        }
      }
    }
#pragma unroll
    for (int r = 0; r < 4; ++r) {
#pragma unroll
      for (int o = 1; o < 16; o <<= 1) u[r] += __shfl_xor(u[r], o);
    }
    if (l15 == 0) {
#pragma unroll
      for (int r = 0; r < 4; ++r) {
        int tl = trow + r;
        if (tl < 200) {
          int t = t0 + tl;
          float uu = u[r];
          if (a.chars[(size_t)b * T_ + t] == 0) uu = 0.f;
          a.ws_u[(size_t)b * T_ + t] = uu;
        }
      }
    }
  }
}

// ---------------------------------------------------------------------------
// Softmax (redundant per tc) + context partial over 200-t chunk. Block (tc,b).
// ---------------------------------------------------------------------------
__global__ __launch_bounds__(256) void ctx_smax_part_kernel(Args a) {
  __shared__ float s_u[T_];
  __shared__ float s_red[8];
  const int tc = blockIdx.x, b = blockIdx.y, tid = threadIdx.x;
  const int lane = tid & 63, wave = tid >> 6;

  float mx = -1e30f;
  for (int t = tid; t < T_; t += 256) {
    float v = a.ws_u[(size_t)b * T_ + t];
    s_u[t] = v;
    mx = fmaxf(mx, v);
  }
#pragma unroll
  for (int o = 32; o >= 1; o >>= 1) mx = fmaxf(mx, __shfl_xor(mx, o));
  if (lane == 0) s_red[wave] = mx;
  __syncthreads();
  mx = fmaxf(fmaxf(s_red[0], s_red[1]), fmaxf(s_red[2], s_red[3]));

  float smv = 0.f;
  for (int t = tid; t < T_; t += 256) {
    float e = __expf(s_u[t] - mx);
    s_u[t] = e;
    smv += e;
  }
#pragma unroll
  for (int o = 32; o >= 1; o >>= 1) smv += __shfl_xor(smv, o);
  if (lane == 0) s_red[4 + wave] = smv;
  __syncthreads();
  smv = s_red[4] + s_red[5] + s_red[6] + s_red[7];
  float inv = 1.f / smv;
  for (int t = tid; t < T_; t += 256) {
    float s = s_u[t] * inv;
    s_u[t] = s;
    if (tc == 0) {
      a.o_scores[(size_t)b * T_ + t] = s;
      a.o_cum[(size_t)b * T_ + t] = a.cum[(size_t)b * T_ + t] + s;
    }
  }
  __syncthreads();

  const int start = tc * 200;
  const float2* Eb = (const float2*)(a.enc + ((size_t)b * T_ + start) * INP) + tid;
  const float* su = &s_u[start];
  float2 a0 = {0.f, 0.f}, a1 = {0.f, 0.f}, a2 = {0.f, 0.f}, a3 = {0.f, 0.f};
  for (int t = 0; t < 200; t += 4) {
    float s0 = su[t], s1 = su[t + 1], s2 = su[t + 2], s3 = su[t + 3];
    float2 e0 = Eb[(size_t)(t)     * 256];
    float2 e1 = Eb[(size_t)(t + 1) * 256];
    float2 e2 = Eb[(size_t)(t + 2) * 256];
    float2 e3 = Eb[(size_t)(t + 3) * 256];
    a0.x += s0 * e0.x; a0.y += s0 * e0.y;
    a1.x += s1 * e1.x; a1.y += s1 * e1.y;
    a2.x += s2 * e2.x; a2.y += s2 * e2.y;
    a3.x += s3 * e3.x; a3.y += s3 * e3.y;
  }
  float2 r;
  r.x = (a0.x + a1.x) + (a2.x + a3.x);
  r.y = (a0.y + a1.y) + (a2.y + a3.y);
  *(float2*)&a.ws_part[((size_t)tc * B_ + b) * INP + 2 * tid] = r;
}

// ---------------------------------------------------------------------------
// Generic bf16-MFMA GEMM (R3-proven) + optional A1-partial-sum staging mode.
// ---------------------------------------------------------------------------
__global__ __launch_bounds__(256) void gemm_bf16(
    const float* __restrict__ A1, const float* __restrict__ A1b,
    float* __restrict__ ctx_side, int lda1,
    const float* __restrict__ W1, int ldw1, int K1,
    const float* __restrict__ A2, int lda2, const float* __restrict__ W2, int ldw2, int K2,
    const float* __restrict__ bias1, const float* __restrict__ bias2,
    float* __restrict__ out, int ldo, int act, int zmode)
{
  __shared__ __align__(16) short sA[64][40];
  __shared__ __align__(16) short sB[64][40];
  const int tid  = threadIdx.x;
  const int lane = tid & 63;
  const int wave = tid >> 6;
  const int wr = (wave >> 1) * 32;
  const int wc = (wave & 1) * 32;
  const int bm = blockIdx.y * 64;
  const int bn = blockIdx.x * 64;
  const int sr = tid >> 2;
  const int sk = (tid & 3) * 8;
  const int l15 = lane & 15;
  const int kq  = (lane >> 4) * 8;

  int kb1 = 0, ke1 = K1, kb2 = 0, ke2 = K2;
  if (zmode == 2) {
    int p = blockIdx.z >> 1, h = blockIdx.z & 1;
    if (p == 0) { ke2 = 0; int half = K1 >> 1; kb1 = h * half; ke1 = kb1 + half; }
    else        { ke1 = 0; int half = K2 >> 1; kb2 = h * half; ke2 = kb2 + half; }
  }
  float* outp = out;
  if (zmode == 2) outp += (size_t)blockIdx.z * (size_t)(gridDim.y * 64) * ldo;

  f32x4 acc[2][2];
#pragma unroll
  for (int i = 0; i < 2; ++i)
#pragma unroll
    for (int j = 0; j < 2; ++j) acc[i][j] = (f32x4){0.f, 0.f, 0.f, 0.f};

  for (int pair = 0; pair < 2; ++pair) {
    const int kb = pair ? kb2 : kb1;
    const int ke = pair ? ke2 : ke1;
    if (ke <= kb) continue;
    const float* A = pair ? A2 : A1;
    const float* Ab = pair ? nullptr : A1b;
    const float* W = pair ? W2 : W1;
    const int lda = pair ? lda2 : lda1;
    const int ldw = pair ? ldw2 : ldw1;
    const float* arow  = A + (size_t)(bm + sr) * lda;
    const float* arowb = Ab ? Ab + (size_t)(bm + sr) * lda : nullptr;
    const float* wrow  = W + (size_t)(bn + sr) * ldw;
    float* crow = (pair == 0 && ctx_side) ? ctx_side + (size_t)(bm + sr) * lda : nullptr;

    float4 ra0, ra1, rb0, rb1;
    if (kb + 32 <= ke) {
      const float* pa = arow + kb + sk;
      const float* pw = wrow + kb + sk;
      ra0 = *(const float4*)pa; ra1 = *(const float4*)(pa + 4);
      if (arowb) {
        const float* pb = arowb + kb + sk;
        float4 b0 = *(const float4*)pb, b1 = *(const float4*)(pb + 4);
        ra0.x += b0.x; ra0.y += b0.y; ra0.z += b0.z; ra0.w += b0.w;
        ra1.x += b1.x; ra1.y += b1.y; ra1.z += b1.z; ra1.w += b1.w;
      }
      rb0 = *(const float4*)pw; rb1 = *(const float4*)(pw + 4);
    }
    for (int k0 = kb; k0 < ke; k0 += 32) {
      __syncthreads();
      if (k0 + 32 <= ke) {
        *(bf16x8*)&sA[sr][sk] = pack8(ra0, ra1);
        *(bf16x8*)&sB[sr][sk] = pack8(rb0, rb1);
        if (crow) {
          *(float4*)(crow + k0 + sk) = ra0;
          *(float4*)(crow + k0 + sk + 4) = ra1;
        }
        if (k0 + 64 <= ke) {
          const float* pa = arow + k0 + 32 + sk;
          const float* pw = wrow + k0 + 32 + sk;
          ra0 = *(const float4*)pa; ra1 = *(const float4*)(pa + 4);
          if (arowb) {
            const float* pb = arowb + k0 + 32 + sk;
            float4 b0 = *(const float4*)pb, b1 = *(const float4*)(pb + 4);
            ra0.x += b0.x; ra0.y += b0.y; ra0.z += b0.z; ra0.w += b0.w;
            ra1.x += b1.x; ra1.y += b1.y; ra1.z += b1.z; ra1.w += b1.w;
          }
          rb0 = *(const float4*)pw; rb1 = *(const float4*)(pw + 4);
        }
      } else {
        short* da = &sA[sr][sk];
        short* db = &sB[sr][sk];
#pragma unroll
        for (int j = 0; j < 8; ++j) {
          int k = k0 + sk + j;
          float av = (k < ke) ? arow[k] + (arowb ? arowb[k] : 0.f) : 0.f;
          da[j] = (k < ke) ? f2bf(av) : (short)0;
          db[j] = (k < ke) ? f2bf(wrow[k]) : (short)0;
        }
      }
      __syncthreads();
      bf16x8 af[2], bfv[2];
      af[0]  = *(const bf16x8*)&sA[wr + l15][kq];
      af[1]  = *(const bf16x8*)&sA[wr + 16 + l15][kq];
      bfv[0] = *(const bf16x8*)&sB[wc + l15][kq];
      bfv[1] = *(const bf16x8*)&sB[wc + 16 + l15][kq];
#pragma unroll
      for (int i = 0; i < 2; ++i)
#pragma unroll
        for (int j = 0; j < 2; ++j)
          acc[i][j] = __builtin_amdgcn_mfma_f32_16x16x32_bf16(af[i], bfv[j], acc[i][j], 0, 0, 0);
    }
  }

#pragma unroll
  for (int i = 0; i < 2; ++i) {
#pragma unroll
    for (int j = 0; j < 2; ++j) {
      int n = bn + wc + j * 16 + l15;
      float bv = 0.f;
      if (zmode == 0) bv = (bias1 ? bias1[n] : 0.f) + (bias2 ? bias2[n] : 0.f);
#pragma unroll
      for (int r = 0; r < 4; ++r) {
        int m = bm + wr + i * 16 + (lane >> 4) * 4 + r;
        float v = acc[i][j][r] + bv;
        if (act == 1) v = fmaxf(v, 0.f);
        outp[(size_t)m * ldo + n] = v;
      }
    }
  }
}

// ---------------------------------------------------------------------------
// LSTM cell (4 gate partials) + residual (R3-proven).
// ---------------------------------------------------------------------------
__global__ __launch_bounds__(256) void lstm_cell_kernel(
    const float* __restrict__ g4, const float* __restrict__ bih,
    const float* __restrict__ bhh, const float* __restrict__ c_old,
    const float* __restrict__ x_in,
    float* __restrict__ h_out, float* __restrict__ c_out,
    float* __restrict__ x_out)
{
  const size_t SEG = (size_t)B_ * 4096;
  int idx = blockIdx.x * 256 + threadIdx.x;
  if (idx >= B_ * LSTM_) return;
  int b = idx >> 10, j = idx & 1023;
  const float* gb = g4 + (size_t)b * 4096;
  float ig = gb[j]        + gb[SEG + j]        + gb[2*SEG + j]        + gb[3*SEG + j]        + bih[j]        + bhh[j];
  float fg = gb[1024 + j] + gb[SEG + 1024 + j] + gb[2*SEG + 1024 + j] + gb[3*SEG + 1024 + j] + bih[1024 + j] + bhh[1024 + j];
  float gg = gb[2048 + j] + gb[SEG + 2048 + j] + gb[2*SEG + 2048 + j] + gb[3*SEG + 2048 + j] + bih[2048 + j] + bhh[2048 + j];
  float og = gb[3072 + j] + gb[SEG + 3072 + j] + gb[2*SEG + 3072 + j] + gb[3*SEG + 3072 + j] + bih[3072 + j] + bhh[3072 + j];
  float cn = sigmoidf_(fg) * c_old[idx] + sigmoidf_(ig) * tanhf_(gg);
  float hn = sigmoidf_(og) * tanhf_(cn);
  h_out[idx] = hn;
  c_out[idx] = cn;
  x_out[idx] = x_in[idx] + hn;
}

// ---------------------------------------------------------------------------
// mel + stop head v2. Block (part, b): part owns 20 mel rows (5 per wave).
// float4 weight loads, 5 concurrent accumulators for ILP. part==0 does stop.
// ---------------------------------------------------------------------------
__global__ __launch_bounds__(256) void mel_stop_kernel(Args a) {
  __shared__ float s_x[LSTM_];
  __shared__ float s_c[INP];
  __shared__ float s_red[4];
  const int part = blockIdx.x;       // 0..3
  const int b    = blockIdx.y;
  const int tid  = threadIdx.x;
  const int lane = tid & 63, wave = tid >> 6;

  for (int k = tid * 4; k < LSTM_; k += 1024)
    *(float4*)&s_x[k] = *(const float4*)&a.ws_x[(size_t)b * LSTM_ + k];
  if (part == 0)
    for (int k = tid; k < INP; k += 256) s_c[k] = a.o_ctx[(size_t)b * INP + k];
  __syncthreads();

  // 5 mel rows per wave, float4 loads, concurrent accumulators
  const int n0 = part * 20 + wave * 5;
  const float* w0 = a.melw + (size_t)(n0)     * MAXR * LSTM_;
  const float* w1 = a.melw + (size_t)(n0 + 1) * MAXR * LSTM_;
  const float* w2 = a.melw + (size_t)(n0 + 2) * MAXR * LSTM_;
  const float* w3 = a.melw + (size_t)(n0 + 3) * MAXR * LSTM_;
  const float* w4 = a.melw + (size_t)(n0 + 4) * MAXR * LSTM_;
  float ac0 = 0.f, ac1 = 0.f, ac2 = 0.f, ac3 = 0.f, ac4 = 0.f;
#pragma unroll
  for (int j = 0; j < 4; ++j) {
    int k = j * 256 + lane * 4;
    float4 xv = *(const float4*)&s_x[k];
    float4 v0 = *(const float4*)(w0 + k);
    float4 v1 = *(const float4*)(w1 + k);
    float4 v2 = *(const float4*)(w2 + k);
    float4 v3 = *(const float4*)(w3 + k);
    float4 v4 = *(const float4*)(w4 + k);
    ac0 += v0.x * xv.x + v0.y * xv.y + v0.z * xv.z + v0.w * xv.w;
    ac1 += v1.x * xv.x + v1.y * xv.y + v1.z * xv.z + v1.w * xv.w;
    ac2 += v2.x * xv.x + v2.y * xv.y + v2.z * xv.z + v2.w * xv.w;
    ac3 += v3.x * xv.x + v3.y * xv.y + v3.z * xv.z + v3.w * xv.w;
    ac4 += v4.x * xv.x + v4.y * xv.y + v4.z * xv.z + v4.w * xv.w;
  }
#pragma unroll
  for (int o = 32; o >= 1; o >>= 1) {
    ac0 += __shfl_xor(ac0, o);
    ac1 += __shfl_xor(ac1, o);
    ac2 += __shfl_xor(ac2, o);
    ac3 += __shfl_xor(ac3, o);
    ac4 += __shfl_xor(ac4, o);
  }
  if (lane == 0) {
    float* om = a.o_mels + (size_t)b * NMELS + n0;
    om[0] = ac0; om[1] = ac1; om[2] = ac2; om[3] = ac3; om[4] = ac4;
  }

  if (part == 0) {
    float p = 0.f;
    for (int k = tid; k < LSTM_; k += 256) p += s_x[k] * a.stopw[k];
    for (int k = tid; k < INP; k += 256) p += s_c[k] * a.stopw[LSTM_ + k];
#pragma unroll
    for (int o = 32; o >= 1; o >>= 1) p += __shfl_xor(p, o);
    if (lane == 0) s_red[wave] = p;
    __syncthreads();
    if (tid == 0) {
      float t = s_red[0] + s_red[1] + s_red[2] + s_red[3] + a.stopb[0];
      a.o_stop[b] = sigmoidf_(t);
    }
  }
}

// ---------------------------------------------------------------------------
extern "C" void kernel_launch(void* const* d_in, const int* in_sizes, int n_in,
                              void* d_out, int out_size, void* d_ws, size_t ws_size,
                              hipStream_t stream) {
  Args a;
  a.enc   = (const float*)d_in[0];
  a.esp   = (const float*)d_in[1];
  a.prein = (const float*)d_in[2];
  a.ah0   = (const float*)d_in[3];
  a.h1_0  = (const float*)d_in[4];
  a.h2_0  = (const float*)d_in[5];
  a.c1_0  = (const float*)d_in[6];
  a.c2_0  = (const float*)d_in[7];
  a.ctx0  = (const float*)d_in[8];
  a.cum   = (const float*)d_in[9];
  a.chars = (const int*)d_in[10];
  a.pw1 = (const float*)d_in[11];  a.pb1 = (const float*)d_in[12];
  a.pw2 = (const float*)d_in[13];  a.pb2 = (const float*)d_in[14];
  a.gwih = (const float*)d_in[15]; a.gwhh = (const float*)d_in[16];
  a.gbih = (const float*)d_in[17]; a.gbhh = (const float*)d_in[18];
  a.cvw = (const float*)d_in[19];  a.cvb = (const float*)d_in[20];
  a.lsaL = (const float*)d_in[21]; a.lsaW = (const float*)d_in[22];
  a.lsaWb = (const float*)d_in[23]; a.lsav = (const float*)d_in[24];
  a.riw = (const float*)d_in[25];  a.rib = (const float*)d_in[26];
  a.l1wih = (const float*)d_in[27]; a.l1whh = (const float*)d_in[28];
  a.l1bih = (const float*)d_in[29]; a.l1bhh = (const float*)d_in[30];
  a.l2wih = (const float*)d_in[31]; a.l2whh = (const float*)d_in[32];
  a.l2bih = (const float*)d_in[33]; a.l2bhh = (const float*)d_in[34];
  a.melw = (const float*)d_in[35]; a.stopw = (const float*)d_in[36];
  a.stopb = (const float*)d_in[37];

  float* out = (float*)d_out;
  a.o_mels   = out;
  a.o_scores = out + 20480;
  a.o_attn   = out + 122880;
  a.o_h1     = out + 155648;
  a.o_h2     = out + 417792;
  a.o_c1     = out + 679936;
  a.o_c2     = out + 942080;
  a.o_ctx    = out + 1204224;
  a.o_stop   = out + 1335296;
  a.o_cum    = out + 1335552;

  float* ws = (float*)d_ws;
  a.ws_pq   = ws;                    // 256*128
  a.ws_u    = ws + 32768;            // 256*400
  a.ws_part = ws + 135168;           // 2*256*512
  a.ws_x    = ws + 397312;           // 256*1024 (x, later reused as x3)
  a.ws_x2   = ws + 659456;           // 256*1024
  a.ws_g4   = ws + 921600;           // 4*256*4096

  dim3 blk(256);

  // 1. fused head: prenet1+prenet2+gi+gh+GRU+pq
  head_kernel<<<dim3(B_), blk, 0, stream>>>(a);
  // 2. attention scores (MFMA)
  attn_score_kernel<<<dim3(2, B_), blk, 0, stream>>>(a);
  // 3. softmax + context partials (TCH=2)
  ctx_smax_part_kernel<<<dim3(TCH, B_), blk, 0, stream>>>(a);
  // 4. rnn_in = [ctx | attn_hidden] @ riw^T + rib (ctx summed in staging)
  gemm_bf16<<<dim3(16, 4, 1), blk, 0, stream>>>(
      a.ws_part, a.ws_part + (size_t)B_ * INP, a.o_ctx, 512,
      a.riw, 640, 512,
      a.o_attn, 128, a.riw + 512, 640, 128,
      a.rib, nullptr, a.ws_x, 1024, 0, 0);
  // 5. LSTM1 gates (K-split partials)
  gemm_bf16<<<dim3(64, 4, 4), blk, 0, stream>>>(
      a.ws_x, nullptr, nullptr, 1024, a.l1wih, 1024, 1024,
      a.h1_0, 1024, a.l1whh, 1024, 1024,
      nullptr, nullptr, a.ws_g4, 4096, 0, 2);
  // 6. LSTM1 cell -> h1,c1 (d_out); x2 = x + h1
  lstm_cell_kernel<<<dim3(1024), blk, 0, stream>>>(
      a.ws_g4, a.l1bih, a.l1bhh, a.c1_0, a.ws_x, a.o_h1, a.o_c1, a.ws_x2);
  // 7. LSTM2 gates
  gemm_bf16<<<dim3(64, 4, 4), blk, 0, stream>>>(
      a.ws_x2, nullptr, nullptr, 1024, a.l2wih, 1024, 1024,
      a.h2_0, 1024, a.l2whh, 1024, 1024,
      nullptr, nullptr, a.ws_g4, 4096, 0, 2);
  // 8. LSTM2 cell -> h2,c2 (d_out); x3 = x2 + h2 (into recycled ws_x)
  lstm_cell_kernel<<<dim3(1024), blk, 0, stream>>>(
      a.ws_g4, a.l2bih, a.l2bhh, a.c2_0, a.ws_x2, a.o_h2, a.o_c2, a.ws_x);
  // 9. mel + stop heads (4 blocks per row)
  mel_stop_kernel<<<dim3(4, B_), blk, 0, stream>>>(a);
}